// Round 5
// baseline (216.451 us; speedup 1.0000x reference)
//
#include <hip/hip_runtime.h>

#define NQ 1024
#define NO 2048
#define LAT 128
#define CHUNK 16
#define NCHUNK (NO / CHUNK)          // 128
#define LOG2E 1.4426950408889634f
#define NEG_BIG -3.0e38f
#define PART_STRIDE 136   // 4 m + 4 lsum + 128 acc (floats per (slot,q))
#define SY_MAX 32

// ---------------------------------------------------------------------------
// value path: h_obs <- LayerNorm(h_obs) @ Wv + bv (in place).
// One obs per block, 256 threads: thread t owns output dim d = t&127 and
// k-half kh = t>>7 (64-step serial chain instead of 128). 2048 blocks ->
// 32 waves/CU (was 4/CU in R4 -> latency-bound, ~50+ us).
// ---------------------------------------------------------------------------
__global__ __launch_bounds__(256) void gano_value(
    const float* __restrict__ ln_g,
    const float* __restrict__ ln_b,
    const float* __restrict__ Wv,
    const float* __restrict__ bv,
    float* __restrict__ h)
{
    __shared__ float hn[LAT];
    __shared__ float red[8];
    __shared__ float part[LAT];
    const int t = threadIdx.x;
    const int o = blockIdx.x;
    const int d = t & 127;
    const int kh = t >> 7;

    const float x = h[(size_t)o*LAT + d];
    float s1 = x, s2 = x*x;
#pragma unroll
    for (int off = 32; off >= 1; off >>= 1) {
        s1 += __shfl_xor(s1, off);
        s2 += __shfl_xor(s2, off);
    }
    const int w = t >> 6;
    if ((t & 63) == 0) { red[w*2] = s1; red[w*2+1] = s2; }
    __syncthreads();
    // waves 0 (dims 0-63) and 1 (dims 64-127) cover all dims once
    const float S1 = red[0] + red[2];
    const float S2 = red[1] + red[3];
    const float mean = S1 * (1.0f/LAT);
    const float var  = S2 * (1.0f/LAT) - mean*mean;
    const float rstd = rsqrtf(var + 1e-5f);
    if (t < LAT)
        hn[d] = (x - mean) * rstd * ln_g[d] + ln_b[d];
    __syncthreads();

    float acc = kh ? 0.f : bv[d];
    const float* wp = Wv + (size_t)(kh*64)*LAT + d;
    const float* hp = hn + kh*64;
#pragma unroll 8
    for (int kk = 0; kk < 64; ++kk)
        acc = fmaf(hp[kk], wp[(size_t)kk*LAT], acc);
    if (kh) part[d] = acc;
    __syncthreads();
    if (!kh) h[(size_t)o*LAT + d] = acc + part[d];
}

// ---------------------------------------------------------------------------
// main: 16 threads per query; thread i owns dims [i*8, i*8+8) (= head i>>2).
// W2 in registers; preact = c_q[d] + d_o[d] + W1[9][d]*dist; relu; logit
// partials -> select-butterfly reduce; online softmax in log2 domain.
// CHUNK=16 -> LDS 18.2 KB -> 8 blocks/CU = 32 waves/CU (R4: 4 blocks, 35%
// occupancy, latency-bound at ~32% real VALU issue).
// LDS float4-group swizzle slot = g ^ (g>>3): 2 addrs/bank-quad (the floor
// for this shape; ~+4 cyc per b128, accepted).
// ---------------------------------------------------------------------------
__global__ __launch_bounds__(256, 2) void gano_main(
    const float* __restrict__ v,          // h_obs buffer, now holding v
    const float* __restrict__ pos_obs,
    const float* __restrict__ pos_query,
    const int* __restrict__ obs_batch,
    const int* __restrict__ query_batch,
    const float* __restrict__ W1,
    const float* __restrict__ b1,
    const float* __restrict__ W2,
    const float* __restrict__ b2,
    float* __restrict__ ws,
    float* __restrict__ out,
    int SY)
{
    __shared__ __align__(16) float ld[CHUNK*LAT];   // d_o tile (swizzled) 8 KB
    __shared__ __align__(16) float lv[CHUNK*LAT];   // v tile   (swizzled) 8 KB
    __shared__ __align__(16) float w1d[3*LAT];      // W1[3+a]-W1[6+a]   1.5 KB
    __shared__ float lpos[CHUNK*3];
    __shared__ int   lob[CHUNK];

    const int tid = threadIdx.x;
    const int i  = tid & 15;        // dim-slice owner within query
    const int qi = tid >> 4;        // query within block (0..15)
    const int q  = blockIdx.x * 16 + qi;
    const int d0 = i * 8;
    const int hstar = i >> 2;       // the head this thread's dims belong to

    // swizzled float offsets of this thread's two float4 groups
    const int g0 = 2*i,     s0 = (g0 ^ (g0 >> 3)) * 4;
    const int g1 = 2*i + 1, s1 = (g1 ^ (g1 >> 3)) * 4;

    // per-block LDS constant (covered by first in-loop barrier)
    for (int idx = tid; idx < 3*LAT; idx += 256) {
        const int a = idx >> 7, dd = idx & 127;
        w1d[idx] = W1[(3+a)*LAT + dd] - W1[(6+a)*LAT + dd];
    }

    const float pqx = pos_query[q*3+0];
    const float pqy = pos_query[q*3+1];
    const float pqz = pos_query[q*3+2];
    const int   qb  = query_batch[q];
    const float b2k = b2[hstar] * LOG2E;

    // registers: W2 rows for my 8 dims (pre-scaled by log2e), c_q, w_dist
    float w2f[8][4], cqf[8], wdf[8];
    {
        const float pq_[3] = {pqx, pqy, pqz};
        float4 c0 = *(const float4*)(b1 + d0);
        float4 c1 = *(const float4*)(b1 + d0 + 4);
#pragma unroll
        for (int a = 0; a < 3; ++a) {
            const float4 w0a = *(const float4*)(W1 + a*LAT + d0);
            const float4 w0b = *(const float4*)(W1 + a*LAT + d0 + 4);
            const float4 w6a = *(const float4*)(W1 + (6+a)*LAT + d0);
            const float4 w6b = *(const float4*)(W1 + (6+a)*LAT + d0 + 4);
            c0.x = fmaf(pq_[a], w0a.x + w6a.x, c0.x);
            c0.y = fmaf(pq_[a], w0a.y + w6a.y, c0.y);
            c0.z = fmaf(pq_[a], w0a.z + w6a.z, c0.z);
            c0.w = fmaf(pq_[a], w0a.w + w6a.w, c0.w);
            c1.x = fmaf(pq_[a], w0b.x + w6b.x, c1.x);
            c1.y = fmaf(pq_[a], w0b.y + w6b.y, c1.y);
            c1.z = fmaf(pq_[a], w0b.z + w6b.z, c1.z);
            c1.w = fmaf(pq_[a], w0b.w + w6b.w, c1.w);
        }
        cqf[0]=c0.x; cqf[1]=c0.y; cqf[2]=c0.z; cqf[3]=c0.w;
        cqf[4]=c1.x; cqf[5]=c1.y; cqf[6]=c1.z; cqf[7]=c1.w;
        const float4 wda = *(const float4*)(W1 + 9*LAT + d0);
        const float4 wdb = *(const float4*)(W1 + 9*LAT + d0 + 4);
        wdf[0]=wda.x; wdf[1]=wda.y; wdf[2]=wda.z; wdf[3]=wda.w;
        wdf[4]=wdb.x; wdf[5]=wdb.y; wdf[6]=wdb.z; wdf[7]=wdb.w;
#pragma unroll
        for (int j = 0; j < 8; ++j) {
            const float4 w = *(const float4*)(W2 + (d0 + j)*4);
            w2f[j][0] = w.x * LOG2E;  w2f[j][1] = w.y * LOG2E;
            w2f[j][2] = w.z * LOG2E;  w2f[j][3] = w.w * LOG2E;
        }
    }

    float4 accA = make_float4(0.f,0.f,0.f,0.f);
    float4 accB = make_float4(0.f,0.f,0.f,0.f);
    float m = NEG_BIG, lsum = 0.f;

    for (int cb = blockIdx.y; cb < NCHUNK; cb += SY) {
        const int o0 = cb * CHUNK;
        __syncthreads();   // previous chunk consumed / w1d ready
        for (int idx = tid; idx < CHUNK*(LAT/4); idx += 256) {
            const int oo = idx >> 5;           // obs within chunk
            const int g  = idx & 31;           // float4 group
            const int d4 = g * 4;
            const int sg = (g ^ (g >> 3)) * 4; // swizzled slot
            const float* po = pos_obs + (size_t)(o0 + oo)*3;
            const float px = po[0], py = po[1], pz = po[2];
            const float4 wa = *(const float4*)(w1d + 0*LAT + d4);
            const float4 wb = *(const float4*)(w1d + 1*LAT + d4);
            const float4 wc = *(const float4*)(w1d + 2*LAT + d4);
            float4 r;
            r.x = fmaf(px, wa.x, fmaf(py, wb.x, pz*wc.x));
            r.y = fmaf(px, wa.y, fmaf(py, wb.y, pz*wc.y));
            r.z = fmaf(px, wa.z, fmaf(py, wb.z, pz*wc.z));
            r.w = fmaf(px, wa.w, fmaf(py, wb.w, pz*wc.w));
            *(float4*)(ld + oo*LAT + sg) = r;
            *(float4*)(lv + oo*LAT + sg) =
                *(const float4*)(v + (size_t)(o0+oo)*LAT + d4);
        }
        for (int idx = tid; idx < CHUNK*3; idx += 256) lpos[idx] = pos_obs[o0*3 + idx];
        for (int idx = tid; idx < CHUNK;   idx += 256) lob[idx]  = obs_batch[o0 + idx];
        __syncthreads();

#pragma unroll 1
        for (int oc = 0; oc < CHUNK; ++oc) {
            const float dx = pqx - lpos[oc*3+0];
            const float dy = pqy - lpos[oc*3+1];
            const float dz = pqz - lpos[oc*3+2];
            const float dist = sqrtf(dx*dx + dy*dy + dz*dz);
            const int mb = (lob[oc] == qb);

            const float* dptr = ld + oc*LAT;
            const float4 dA = *(const float4*)(dptr + s0);
            const float4 dB = *(const float4*)(dptr + s1);
            const float dval[8] = {dA.x, dA.y, dA.z, dA.w,
                                   dB.x, dB.y, dB.z, dB.w};
            float lg0 = 0.f, lg1 = 0.f, lg2 = 0.f, lg3 = 0.f;
#pragma unroll
            for (int j = 0; j < 8; ++j) {
                const float hj = fmaxf(fmaf(wdf[j], dist, cqf[j] + dval[j]), 0.f);
                lg0 = fmaf(hj, w2f[j][0], lg0);
                lg1 = fmaf(hj, w2f[j][1], lg1);
                lg2 = fmaf(hj, w2f[j][2], lg2);
                lg3 = fmaf(hj, w2f[j][3], lg3);
            }
            // reduce over the 16-lane group: fold to 4-lane classes, select
            // own head's partial, finish within the 4-lane subgroup
            lg0 += __shfl_xor(lg0, 8); lg0 += __shfl_xor(lg0, 4);
            lg1 += __shfl_xor(lg1, 8); lg1 += __shfl_xor(lg1, 4);
            lg2 += __shfl_xor(lg2, 8); lg2 += __shfl_xor(lg2, 4);
            lg3 += __shfl_xor(lg3, 8); lg3 += __shfl_xor(lg3, 4);
            float sel = (i & 8) ? ((i & 4) ? lg3 : lg2)
                                : ((i & 4) ? lg1 : lg0);
            sel += __shfl_xor(sel, 1);
            sel += __shfl_xor(sel, 2);

            float logit = sel + b2k;
            logit = mb ? logit : NEG_BIG;

            const float mn    = fmaxf(m, logit);
            const float alpha = exp2f(m - mn);
            const float p     = mb ? exp2f(logit - mn) : 0.f;
            lsum = fmaf(lsum, alpha, p);
            m = mn;

            const float* vptr = lv + oc*LAT;
            const float4 vA = *(const float4*)(vptr + s0);
            const float4 vB = *(const float4*)(vptr + s1);
            accA.x = fmaf(accA.x, alpha, p*vA.x);
            accA.y = fmaf(accA.y, alpha, p*vA.y);
            accA.z = fmaf(accA.z, alpha, p*vA.z);
            accA.w = fmaf(accA.w, alpha, p*vA.w);
            accB.x = fmaf(accB.x, alpha, p*vB.x);
            accB.y = fmaf(accB.y, alpha, p*vB.y);
            accB.z = fmaf(accB.z, alpha, p*vB.z);
            accB.w = fmaf(accB.w, alpha, p*vB.w);
        }
    }

    if (SY == 1) {
        const float inv = 1.0f / lsum;
        float* op = out + (size_t)q*LAT + d0;
        float4 rA, rB;
        rA.x = accA.x*inv; rA.y = accA.y*inv; rA.z = accA.z*inv; rA.w = accA.w*inv;
        rB.x = accB.x*inv; rB.y = accB.y*inv; rB.z = accB.z*inv; rB.w = accB.w*inv;
        *(float4*)op       = rA;
        *(float4*)(op + 4) = rB;
    } else {
        float* pp = ws + ((size_t)blockIdx.y * NQ + q) * PART_STRIDE;
        if ((i & 3) == 0) {          // one writer per head
            pp[hstar]     = m;
            pp[4 + hstar] = lsum;
        }
        *(float4*)(pp + 8 + d0)     = accA;   // dims stored unswizzled
        *(float4*)(pp + 8 + d0 + 4) = accB;
    }
}

// ---------------------------------------------------------------------------
// combine: merge SY partials per query (log2-domain online merge), normalize
// ---------------------------------------------------------------------------
__global__ __launch_bounds__(128) void gano_combine(
    const float* __restrict__ ws, float* __restrict__ out, int SY)
{
    const int q = blockIdx.x;
    const int l = threadIdx.x;
    const int h = l >> 5;
    float M = NEG_BIG, Ls = 0.f, A = 0.f;
    for (int s = 0; s < SY; ++s) {
        const float* pp = ws + ((size_t)s * NQ + q) * PART_STRIDE;
        const float ms = pp[h];
        const float ls = pp[4 + h];
        const float as = pp[8 + l];
        const float Mn = fmaxf(M, ms);
        const float a0 = exp2f(M - Mn);
        const float a1 = exp2f(ms - Mn);
        Ls = Ls*a0 + ls*a1;
        A  = A *a0 + as*a1;
        M = Mn;
    }
    out[(size_t)q*LAT + l] = A / Ls;
}

// ---------------------------------------------------------------------------
extern "C" void kernel_launch(void* const* d_in, const int* in_sizes, int n_in,
                              void* d_out, int out_size, void* d_ws, size_t ws_size,
                              hipStream_t stream) {
    (void)in_sizes; (void)n_in; (void)out_size;
    float*       h_obs     = (float*)d_in[0];        // mutated in place -> v
    const float* pos_obs   = (const float*)d_in[1];
    const float* pos_query = (const float*)d_in[2];
    const int*   obs_batch = (const int*)d_in[3];
    const int*   query_batch = (const int*)d_in[4];
    const float* W1 = (const float*)d_in[5];
    const float* b1 = (const float*)d_in[6];
    const float* W2 = (const float*)d_in[7];
    const float* b2 = (const float*)d_in[8];
    const float* ln_g = (const float*)d_in[9];
    const float* ln_b = (const float*)d_in[10];
    const float* Wv = (const float*)d_in[11];
    const float* bv = (const float*)d_in[12];
    float* ws  = (float*)d_ws;
    float* out = (float*)d_out;

    // split-O factor: 32 -> grid 64x32 = 2048 blocks = 8/CU exactly.
    // Strictly bounded by what d_ws can hold (0 bytes touched @ SY=1).
    int SY = 1;
    const size_t per = (size_t)NQ * PART_STRIDE * sizeof(float);
    if (ws && ws_size >= 2*per) {
        size_t s = ws_size / per;
        SY = (int)(s < SY_MAX ? s : SY_MAX);
    }

    gano_value<<<NO, 256, 0, stream>>>(ln_g, ln_b, Wv, bv, h_obs);
    gano_main<<<dim3(NQ/16, SY), 256, 0, stream>>>(h_obs, pos_obs, pos_query,
                                                   obs_batch, query_batch,
                                                   W1, b1, W2, b2, ws, out, SY);
    if (SY > 1)
        gano_combine<<<NQ, 128, 0, stream>>>(ws, out, SY);
}

// Round 6
// 189.629 us; speedup vs baseline: 1.1414x; 1.1414x over previous
//
#include <hip/hip_runtime.h>

#define NQ 1024
#define NO 2048
#define LAT 128
#define CHUNK 16
#define NCHUNK (NO / CHUNK)          // 128
#define LOG2E 1.4426950408889634f
#define NEG_BIG -3.0e38f
#define MASK_THRESH -1.0e37f
#define PART_STRIDE 136   // 4 m + 4 lsum + 128 acc (floats per (slot,q))
#define SY_MAX 32

// ---------------------------------------------------------------------------
// value path: h_obs <- LayerNorm(h_obs) @ Wv + bv (in place).
// ---------------------------------------------------------------------------
__global__ __launch_bounds__(256) void gano_value(
    const float* __restrict__ ln_g,
    const float* __restrict__ ln_b,
    const float* __restrict__ Wv,
    const float* __restrict__ bv,
    float* __restrict__ h)
{
    __shared__ float hn[LAT];
    __shared__ float red[8];
    __shared__ float part[LAT];
    const int t = threadIdx.x;
    const int o = blockIdx.x;
    const int d = t & 127;
    const int kh = t >> 7;

    const float x = h[(size_t)o*LAT + d];
    float s1 = x, s2 = x*x;
#pragma unroll
    for (int off = 32; off >= 1; off >>= 1) {
        s1 += __shfl_xor(s1, off);
        s2 += __shfl_xor(s2, off);
    }
    const int w = t >> 6;
    if ((t & 63) == 0) { red[w*2] = s1; red[w*2+1] = s2; }
    __syncthreads();
    const float S1 = red[0] + red[2];
    const float S2 = red[1] + red[3];
    const float mean = S1 * (1.0f/LAT);
    const float var  = S2 * (1.0f/LAT) - mean*mean;
    const float rstd = rsqrtf(var + 1e-5f);
    if (t < LAT)
        hn[d] = (x - mean) * rstd * ln_g[d] + ln_b[d];
    __syncthreads();

    float acc = kh ? 0.f : bv[d];
    const float* wp = Wv + (size_t)(kh*64)*LAT + d;
    const float* hp = hn + kh*64;
#pragma unroll 8
    for (int kk = 0; kk < 64; ++kk)
        acc = fmaf(hp[kk], wp[(size_t)kk*LAT], acc);
    if (kh) part[d] = acc;
    __syncthreads();
    if (!kh) h[(size_t)o*LAT + d] = acc + part[d];
}

// ---------------------------------------------------------------------------
// main, two-phase per chunk (NO cross-lane shuffles — R5 showed the 14
// ds_swizzles/oc saturated the per-CU LDS pipe at ~135 cyc/wave-oc):
//  Phase 1: thread (qi,oc) computes the FULL 128-dim MLP logit for its own
//   (q,oc) pair. c_q from LDS (qi-rotated), d_o from LDS (oc-rotated),
//   wd/W2/b2 via loop-uniform GLOBAL indices -> scalar loads (SMEM pipe).
//   Masked log2-domain logits -> LDS [q][h][oc] (qi-rotated oc).
//  Phase 2: thread (qi,i) owns dims [i*8,i*8+8); reads its head's 16 logits
//   (4x b128), runs online softmax REDUNDANTLY (4 threads per head compute
//   identical m/lsum — redundancy instead of communication), v read straight
//   from GLOBAL (VMEM pipe; L1/L2-resident 1 MB) — no lv staging.
// LDS 17.1 KB; rotations keep every ds access <=2-way (free per m136).
// ---------------------------------------------------------------------------
__global__ __launch_bounds__(256) void gano_main(
    const float* __restrict__ v,          // h_obs buffer, now holding v
    const float* __restrict__ pos_obs,
    const float* __restrict__ pos_query,
    const int* __restrict__ obs_batch,
    const int* __restrict__ query_batch,
    const float* __restrict__ W1,
    const float* __restrict__ b1,
    const float* __restrict__ W2,
    const float* __restrict__ b2,
    float* __restrict__ ws,
    float* __restrict__ out,
    int SY)
{
    __shared__ __align__(16) float ld[CHUNK*LAT];    // d_o tile, oc-rotated 8 KB
    __shared__ __align__(16) float lcq[16*LAT];      // c_q, qi-rotated      8 KB -> 2 KB? (16*128*4 = 8 KB)
    __shared__ __align__(16) float lgt[16*4*CHUNK];  // logits [q][h][oc']   4 KB
    __shared__ __align__(16) float w1d[3*LAT];       // W1[3+a]-W1[6+a]    1.5 KB
    __shared__ float lpos[CHUNK*3];
    __shared__ int   lob[CHUNK];

    const int tid = threadIdx.x;
    const int i  = tid & 15;        // phase1: oc ; phase2: dim-slice
    const int qi = tid >> 4;        // query within block
    const int q  = blockIdx.x * 16 + qi;
    const int d0 = i * 8;           // phase-2 dims
    const int hstar = i >> 2;       // phase-2 head

    // ---- block-init: w1d and c_q into LDS ----
    for (int idx = tid; idx < 3*LAT; idx += 256) {
        const int a = idx >> 7, dd = idx & 127;
        w1d[idx] = W1[(3+a)*LAT + dd] - W1[(6+a)*LAT + dd];
    }
#pragma unroll
    for (int t2 = 0; t2 < 2; ++t2) {
        const int idx = tid + t2*256;
        const int row = idx >> 5;            // query 0..15
        const int g   = idx & 31;            // logical float4 group
        const int dd  = g * 4;
        const int qq  = blockIdx.x * 16 + row;
        const float px = pos_query[qq*3+0];
        const float py = pos_query[qq*3+1];
        const float pz = pos_query[qq*3+2];
        float4 c = *(const float4*)(b1 + dd);
        const float4 wx0 = *(const float4*)(W1 + 0*LAT + dd);
        const float4 wx6 = *(const float4*)(W1 + 6*LAT + dd);
        const float4 wy0 = *(const float4*)(W1 + 1*LAT + dd);
        const float4 wy6 = *(const float4*)(W1 + 7*LAT + dd);
        const float4 wz0 = *(const float4*)(W1 + 2*LAT + dd);
        const float4 wz6 = *(const float4*)(W1 + 8*LAT + dd);
        c.x = fmaf(px, wx0.x+wx6.x, fmaf(py, wy0.x+wy6.x, fmaf(pz, wz0.x+wz6.x, c.x)));
        c.y = fmaf(px, wx0.y+wx6.y, fmaf(py, wy0.y+wy6.y, fmaf(pz, wz0.y+wz6.y, c.y)));
        c.z = fmaf(px, wx0.z+wx6.z, fmaf(py, wy0.z+wy6.z, fmaf(pz, wz0.z+wz6.z, c.z)));
        c.w = fmaf(px, wx0.w+wx6.w, fmaf(py, wy0.w+wy6.w, fmaf(pz, wz0.w+wz6.w, c.w)));
        *(float4*)(lcq + row*LAT + ((g + row) & 31) * 4) = c;
    }

    const int   qb  = query_batch[q];

    float4 accA = make_float4(0.f,0.f,0.f,0.f);
    float4 accB = make_float4(0.f,0.f,0.f,0.f);
    float m = NEG_BIG, lsum = 0.f;

    for (int cb = blockIdx.y; cb < NCHUNK; cb += SY) {
        const int o0 = cb * CHUNK;
        __syncthreads();   // prior phase-2 lgt reads done; lcq/w1d ready (1st)

        // ---- stage d_o (oc-rotated), lpos, lob ----
        for (int idx = tid; idx < CHUNK*(LAT/4); idx += 256) {
            const int oo = idx >> 5;           // obs within chunk
            const int g  = idx & 31;           // logical float4 group
            const int d4 = g * 4;
            const float* po = pos_obs + (size_t)(o0 + oo)*3;
            const float px = po[0], py = po[1], pz = po[2];
            const float4 wa = *(const float4*)(w1d + 0*LAT + d4);
            const float4 wb = *(const float4*)(w1d + 1*LAT + d4);
            const float4 wc = *(const float4*)(w1d + 2*LAT + d4);
            float4 r;
            r.x = fmaf(px, wa.x, fmaf(py, wb.x, pz*wc.x));
            r.y = fmaf(px, wa.y, fmaf(py, wb.y, pz*wc.y));
            r.z = fmaf(px, wa.z, fmaf(py, wb.z, pz*wc.z));
            r.w = fmaf(px, wa.w, fmaf(py, wb.w, pz*wc.w));
            *(float4*)(ld + oo*LAT + ((g + oo) & 31) * 4) = r;
        }
        for (int idx = tid; idx < CHUNK*3; idx += 256) lpos[idx] = pos_obs[o0*3 + idx];
        for (int idx = tid; idx < CHUNK;   idx += 256) lob[idx]  = obs_batch[o0 + idx];
        __syncthreads();

        // ---- phase 1: one full logit per thread, no reduction ----
        {
            const int oc = i;
            const float dx = pos_query[q*3+0] - lpos[oc*3+0];
            const float dy = pos_query[q*3+1] - lpos[oc*3+1];
            const float dz = pos_query[q*3+2] - lpos[oc*3+2];
            const float dist = sqrtf(dx*dx + dy*dy + dz*dz);
            const int mb = (lob[oc] == qb);

            float lg0 = 0.f, lg1 = 0.f, lg2 = 0.f, lg3 = 0.f;
            const float* ldr = ld + oc*LAT;
            const float* lcr = lcq + qi*LAT;
#pragma unroll 4
            for (int j = 0; j < 32; ++j) {
                const float4 dd = *(const float4*)(ldr + ((j + oc) & 31) * 4);
                const float4 cc = *(const float4*)(lcr + ((j + qi) & 31) * 4);
                const float4 wd = *(const float4*)(W1 + 9*LAT + j*4);   // uniform -> s_load
                const float4 w2a = *(const float4*)(W2 + (j*4+0)*4);    // uniform
                const float4 w2b = *(const float4*)(W2 + (j*4+1)*4);
                const float4 w2c = *(const float4*)(W2 + (j*4+2)*4);
                const float4 w2d = *(const float4*)(W2 + (j*4+3)*4);
                const float h0 = fmaxf(fmaf(wd.x, dist, cc.x + dd.x), 0.f);
                const float h1 = fmaxf(fmaf(wd.y, dist, cc.y + dd.y), 0.f);
                const float h2 = fmaxf(fmaf(wd.z, dist, cc.z + dd.z), 0.f);
                const float h3 = fmaxf(fmaf(wd.w, dist, cc.w + dd.w), 0.f);
                lg0 = fmaf(h0, w2a.x, lg0); lg1 = fmaf(h0, w2a.y, lg1);
                lg2 = fmaf(h0, w2a.z, lg2); lg3 = fmaf(h0, w2a.w, lg3);
                lg0 = fmaf(h1, w2b.x, lg0); lg1 = fmaf(h1, w2b.y, lg1);
                lg2 = fmaf(h1, w2b.z, lg2); lg3 = fmaf(h1, w2b.w, lg3);
                lg0 = fmaf(h2, w2c.x, lg0); lg1 = fmaf(h2, w2c.y, lg1);
                lg2 = fmaf(h2, w2c.z, lg2); lg3 = fmaf(h2, w2c.w, lg3);
                lg0 = fmaf(h3, w2d.x, lg0); lg1 = fmaf(h3, w2d.y, lg1);
                lg2 = fmaf(h3, w2d.z, lg2); lg3 = fmaf(h3, w2d.w, lg3);
            }
            // log2-domain, fold b2, apply mask; store qi-rotated
            const int ocr = (oc + 4*qi) & 15;
            float* lrow = lgt + (qi*4)*CHUNK + ocr;
            lrow[0*CHUNK] = mb ? fmaf(lg0, LOG2E, b2[0]*LOG2E) : NEG_BIG;
            lrow[1*CHUNK] = mb ? fmaf(lg1, LOG2E, b2[1]*LOG2E) : NEG_BIG;
            lrow[2*CHUNK] = mb ? fmaf(lg2, LOG2E, b2[2]*LOG2E) : NEG_BIG;
            lrow[3*CHUNK] = mb ? fmaf(lg3, LOG2E, b2[3]*LOG2E) : NEG_BIG;
        }
        __syncthreads();

        // ---- phase 2: online softmax + aggregation (v from global) ----
        {
            const float* rowp = lgt + (qi*4 + hstar)*CHUNK;
            float lgv[16];
#pragma unroll
            for (int p = 0; p < 4; ++p) {
                const float4 t = *(const float4*)(rowp + ((p + qi) & 3) * 4);
                lgv[p*4+0] = t.x; lgv[p*4+1] = t.y;
                lgv[p*4+2] = t.z; lgv[p*4+3] = t.w;
            }
#pragma unroll 4
            for (int oc = 0; oc < CHUNK; ++oc) {
                const float lg = lgv[oc];
                const float mn    = fmaxf(m, lg);
                const float alpha = exp2f(m - mn);
                const float p     = (lg > MASK_THRESH) ? exp2f(lg - mn) : 0.f;
                lsum = fmaf(lsum, alpha, p);
                m = mn;
                const float* vp = v + (size_t)(o0 + oc)*LAT + d0;
                const float4 vA = *(const float4*)vp;
                const float4 vB = *(const float4*)(vp + 4);
                accA.x = fmaf(accA.x, alpha, p*vA.x);
                accA.y = fmaf(accA.y, alpha, p*vA.y);
                accA.z = fmaf(accA.z, alpha, p*vA.z);
                accA.w = fmaf(accA.w, alpha, p*vA.w);
                accB.x = fmaf(accB.x, alpha, p*vB.x);
                accB.y = fmaf(accB.y, alpha, p*vB.y);
                accB.z = fmaf(accB.z, alpha, p*vB.z);
                accB.w = fmaf(accB.w, alpha, p*vB.w);
            }
        }
    }

    if (SY == 1) {
        const float inv = 1.0f / lsum;
        float* op = out + (size_t)q*LAT + d0;
        float4 rA, rB;
        rA.x = accA.x*inv; rA.y = accA.y*inv; rA.z = accA.z*inv; rA.w = accA.w*inv;
        rB.x = accB.x*inv; rB.y = accB.y*inv; rB.z = accB.z*inv; rB.w = accB.w*inv;
        *(float4*)op       = rA;
        *(float4*)(op + 4) = rB;
    } else {
        float* pp = ws + ((size_t)blockIdx.y * NQ + q) * PART_STRIDE;
        if ((i & 3) == 0) {          // one writer per head (redundant values identical)
            pp[hstar]     = m;
            pp[4 + hstar] = lsum;
        }
        *(float4*)(pp + 8 + d0)     = accA;
        *(float4*)(pp + 8 + d0 + 4) = accB;
    }
}

// ---------------------------------------------------------------------------
// combine: merge SY partials per query (log2-domain online merge), normalize
// ---------------------------------------------------------------------------
__global__ __launch_bounds__(128) void gano_combine(
    const float* __restrict__ ws, float* __restrict__ out, int SY)
{
    const int q = blockIdx.x;
    const int l = threadIdx.x;
    const int h = l >> 5;
    float M = NEG_BIG, Ls = 0.f, A = 0.f;
    for (int s = 0; s < SY; ++s) {
        const float* pp = ws + ((size_t)s * NQ + q) * PART_STRIDE;
        const float ms = pp[h];
        const float ls = pp[4 + h];
        const float as = pp[8 + l];
        const float Mn = fmaxf(M, ms);
        const float a0 = exp2f(M - Mn);
        const float a1 = exp2f(ms - Mn);
        Ls = Ls*a0 + ls*a1;
        A  = A *a0 + as*a1;
        M = Mn;
    }
    out[(size_t)q*LAT + l] = A / Ls;
}

// ---------------------------------------------------------------------------
extern "C" void kernel_launch(void* const* d_in, const int* in_sizes, int n_in,
                              void* d_out, int out_size, void* d_ws, size_t ws_size,
                              hipStream_t stream) {
    (void)in_sizes; (void)n_in; (void)out_size;
    float*       h_obs     = (float*)d_in[0];        // mutated in place -> v
    const float* pos_obs   = (const float*)d_in[1];
    const float* pos_query = (const float*)d_in[2];
    const int*   obs_batch = (const int*)d_in[3];
    const int*   query_batch = (const int*)d_in[4];
    const float* W1 = (const float*)d_in[5];
    const float* b1 = (const float*)d_in[6];
    const float* W2 = (const float*)d_in[7];
    const float* b2 = (const float*)d_in[8];
    const float* ln_g = (const float*)d_in[9];
    const float* ln_b = (const float*)d_in[10];
    const float* Wv = (const float*)d_in[11];
    const float* bv = (const float*)d_in[12];
    float* ws  = (float*)d_ws;
    float* out = (float*)d_out;

    // split-O factor: 32 -> grid 64x32 = 2048 blocks = 8/CU.
    // Strictly bounded by what d_ws can hold (0 bytes touched @ SY=1).
    int SY = 1;
    const size_t per = (size_t)NQ * PART_STRIDE * sizeof(float);
    if (ws && ws_size >= 2*per) {
        size_t s = ws_size / per;
        SY = (int)(s < SY_MAX ? s : SY_MAX);
    }

    gano_value<<<NO, 256, 0, stream>>>(ln_g, ln_b, Wv, bv, h_obs);
    gano_main<<<dim3(NQ/16, SY), 256, 0, stream>>>(h_obs, pos_obs, pos_query,
                                                   obs_batch, query_batch,
                                                   W1, b1, W2, b2, ws, out, SY);
    if (SY > 1)
        gano_combine<<<NQ, 128, 0, stream>>>(ws, out, SY);
}